// Round 6
// baseline (310.274 us; speedup 1.0000x reference)
//
#include <hip/hip_runtime.h>
#include <cstdint>
#include <cstddef>

#define NN 64
#define CC 192
#define VV 25
#define TTT 300
#define TCH 6           // t per block, one per wave
#define NCH 50          // 300/6
#define GRID (NN*NCH)   // 3200
#define ROWB 384        // X row bytes (192 c * 2B), XOR-swizzled
#define YROWB 80        // Y slice row bytes (32 c1 * 2B + 16B pad)
#define X_BYTES 57600   // 150 rows * 384
#define SW_BYTES 3024   // per-wave scratch: Y slice (<=2544B used) / SIM 27x28 f32
#define LDS_BYTES (X_BYTES + 6*SW_BYTES)  // 75,744 -> 2 blocks/CU
#define WMB_OFF 36864   // u16 elements into ws: wm bf16[192]

typedef unsigned short u16;
typedef unsigned long long u64;
typedef short bf16x8 __attribute__((ext_vector_type(8)));
typedef float f32x4 __attribute__((ext_vector_type(4)));
typedef float f2 __attribute__((ext_vector_type(2)));
typedef u64 u64x2 __attribute__((ext_vector_type(2)));

__device__ __forceinline__ u16 f2bf(float x) {
  union { float f; uint32_t u; } v; v.f = x;
  uint32_t r = v.u + 0x7fffu + ((v.u >> 16) & 1u);
  return (u16)(r >> 16);
}
__device__ __forceinline__ u64 pack4(f32x4 a) {
  return (u64)f2bf(a[0]) | ((u64)f2bf(a[1]) << 16) |
         ((u64)f2bf(a[2]) << 32) | ((u64)f2bf(a[3]) << 48);
}
// XOR swizzle on 384B rows (384 ≡ 0 mod 128 -> every row starts at bank 0 without it)
__device__ __forceinline__ int swz(int row, int colb) {
  return row * ROWB + (colb ^ ((row & 7) << 4));
}

// blocks 0..191: M[c1][c2] = sum_d w1[d][c1]*w2[d][c2] (bf16). block 192: wm -> bf16.
__global__ __launch_bounds__(192) void prep(const float* __restrict__ w1,
                                            const float* __restrict__ w2,
                                            const float* __restrict__ wm,
                                            u16* __restrict__ mb) {
  int c2 = threadIdx.x;
  int b = blockIdx.x;
  if (b < CC) {
    float s = 0.f;
    for (int d = 0; d < CC; ++d) s += w1[d * CC + b] * w2[d * CC + c2];
    mb[b * CC + c2] = f2bf(s);
  } else {
    mb[WMB_OFF + c2] = f2bf(wm[c2]);
  }
}

// One block = (n, 6 t). One staging barrier; then each wave independently computes
// its own t: per c1-chunk {pass1 Y-chunk -> private LDS slice; pass2 sim += X^T Y;
// mask MFMA}; wave-private epilogue (stats, centering, softmax, coalesced store).
__global__ __launch_bounds__(384, 3) void fused(const float* __restrict__ x1,
                                                const u16* __restrict__ mb,
                                                float* __restrict__ out) {
  extern __shared__ char lds[];
  char* XT = lds;                                  // 150 rows x 384B
  const int tid = threadIdx.x;
  const int wid = tid >> 6;
  const int lane = tid & 63;
  const int lr = lane & 15;
  const int lq = lane >> 4;
  char* SW = lds + X_BYTES + wid * SW_BYTES;       // wave-private
  float* SIMW = (float*)SW;                        // epilogue: [27][28] f32

  // XCD-chunked bijective swizzle (GRID % 8 == 0): adjacent-t blocks share L2 lines.
  int b = blockIdx.x;
  int logical = (b & 7) * (GRID / 8) + (b >> 3);
  int n = logical / NCH;
  int tch = logical - n * NCH;
  int t0 = tch * TCH;

  // ---- stage X -> XT[row = tt*25+v][c] bf16 swizzled; f2 loads along t ----
  const float* xb = x1 + (size_t)n * (CC * VV * TTT) + t0;
  for (int job = tid; job < 1800; job += 384) {
    int co = job / 75;                  // c-octet
    int r = job - co * 75;
    int v = r / 3;
    int seg = r - v * 3;                // t-pair
    const float* p = xb + (size_t)(co * 8 * VV + v) * TTT + seg * 2;
    f2 a[8];
    #pragma unroll
    for (int i = 0; i < 8; ++i) a[i] = *(const f2*)(p + (size_t)i * (VV * TTT));
    #pragma unroll
    for (int dt = 0; dt < 2; ++dt) {
      int row = (seg * 2 + dt) * VV + v;
      u64 lo = (u64)f2bf(a[0][dt]) | ((u64)f2bf(a[1][dt]) << 16) |
               ((u64)f2bf(a[2][dt]) << 32) | ((u64)f2bf(a[3][dt]) << 48);
      u64 hi = (u64)f2bf(a[4][dt]) | ((u64)f2bf(a[5][dt]) << 16) |
               ((u64)f2bf(a[6][dt]) << 32) | ((u64)f2bf(a[7][dt]) << 48);
      *(u64x2*)(XT + swz(row, co * 16)) = (u64x2){lo, hi};
    }
  }
  __syncthreads();  // the only barrier

  const int rowbase = wid * VV;  // this wave's t-slice rows in XT
  f32x4 pacc[2][2], macc[2];
  #pragma unroll
  for (int i = 0; i < 2; ++i) {
    macc[i] = (f32x4){0.f, 0.f, 0.f, 0.f};
    #pragma unroll
    for (int jx = 0; jx < 2; ++jx) pacc[i][jx] = (f32x4){0.f, 0.f, 0.f, 0.f};
  }

  // ---- per-wave chunk loop over c1 (6 chunks of 32), no barriers ----
  for (int cc = 0; cc < 6; ++cc) {
    // hoisted M A-fragments (j-invariant): 12 x 16B from L1/L2
    bf16x8 af0[6], af1[6];
    #pragma unroll
    for (int ks = 0; ks < 6; ++ks) {
      af0[ks] = *(const bf16x8*)(mb + (cc * 32 + lr) * CC + ks * 32 + lq * 8);
      af1[ks] = *(const bf16x8*)(mb + (cc * 32 + 16 + lr) * CC + ks * 32 + lq * 8);
    }
    // pass1: Y-chunk[32 c1][32 cols] -> private slice (rows = col, YROWB stride)
    #pragma unroll
    for (int j = 0; j < 2; ++j) {
      f32x4 y0 = (f32x4){0.f, 0.f, 0.f, 0.f};
      f32x4 y1 = (f32x4){0.f, 0.f, 0.f, 0.f};
      #pragma unroll
      for (int ks = 0; ks < 6; ++ks) {
        bf16x8 bb = *(const bf16x8*)(XT + swz(rowbase + j * 16 + lr, ks * 64 + lq * 16));
        y0 = __builtin_amdgcn_mfma_f32_16x16x32_bf16(af0[ks], bb, y0, 0, 0, 0);
        y1 = __builtin_amdgcn_mfma_f32_16x16x32_bf16(af1[ks], bb, y1, 0, 0, 0);
      }
      *(u64*)(SW + (j * 16 + lr) * YROWB + lq * 8) = pack4(y0);
      *(u64*)(SW + (j * 16 + lr) * YROWB + 32 + lq * 8) = pack4(y1);
    }
    // pass2 + mask (same-wave ordering, no barrier needed)
    bf16x8 wmf = *(const bf16x8*)(mb + WMB_OFF + cc * 32 + lq * 8);
    #pragma unroll
    for (int vt = 0; vt < 2; ++vt) {
      bf16x8 A = *(const bf16x8*)(XT + swz(rowbase + vt * 16 + lr, cc * 64 + lq * 16));
      macc[vt] = __builtin_amdgcn_mfma_f32_16x16x32_bf16(A, wmf, macc[vt], 0, 0, 0);
      #pragma unroll
      for (int wt = 0; wt < 2; ++wt) {
        bf16x8 B = *(const bf16x8*)(SW + (wt * 16 + lr) * YROWB + lq * 16);
        pacc[vt][wt] = __builtin_amdgcn_mfma_f32_16x16x32_bf16(A, B, pacc[vt][wt], 0, 0, 0);
      }
    }
  }

  // ---- wave-private epilogue (Y slice dead; reuse as SIM [27][28] f32) ----
  // spill sim' (guards drop garbage rows/cols >= 25)
  #pragma unroll
  for (int vt = 0; vt < 2; ++vt)
    #pragma unroll
    for (int wt = 0; wt < 2; ++wt) {
      int w = wt * 16 + lr;
      if (w < VV) {
        #pragma unroll
        for (int i = 0; i < 4; ++i) {
          int v = vt * 16 + lq * 4 + i;
          if (v < VV) SIMW[v * 28 + w] = pacc[vt][wt][i];
        }
      }
    }
  // mask row (row 26): macc same across lr; lanes lr==0 write
  if (lr == 0) {
    #pragma unroll
    for (int j = 0; j < 2; ++j)
      #pragma unroll
      for (int i = 0; i < 4; ++i) {
        int v = j * 16 + lq * 4 + i;
        if (v < VV) SIMW[26 * 28 + v] = macc[j][i];
      }
  }

  // stats: lane k<25 computes rowsum(k) (kept in reg) and colsum(k) (row 25)
  float rs = 0.f, cs = 0.f;
  if (lane < VV) {
    #pragma unroll
    for (int w = 0; w < VV; ++w) rs += SIMW[lane * 28 + w];
    #pragma unroll
    for (int v = 0; v < VV; ++v) cs += SIMW[v * 28 + lane];
    SIMW[25 * 28 + lane] = cs;
  }
  float x = (lane < VV) ? cs : 0.f;
  #pragma unroll
  for (int s = 1; s < 64; s <<= 1) x += __shfl_xor(x, s);
  const float tot = x;

  // centering + mask + softmax; probs written back to SIM rows
  if (lane < VV) {
    const int v = lane;
    const float base = -rs * 0.04f + tot * 0.0016f;
    const float isc = 0.07216878364870323f;  // 1/sqrt(192)
    float l[VV];
    float mx = -1e30f;
    #pragma unroll
    for (int w = 0; w < VV; ++w) {
      float val = (SIMW[v * 28 + w] - SIMW[25 * 28 + w] * 0.04f + base) * isc +
                  SIMW[26 * 28 + w];
      l[w] = val;
      mx = fmaxf(mx, val);
    }
    float sum = 0.f;
    #pragma unroll
    for (int w = 0; w < VV; ++w) { float e = __expf(l[w] - mx); l[w] = e; sum += e; }
    float rsc = 1.0f / sum;
    #pragma unroll
    for (int w = 0; w < VV; ++w) SIMW[v * 28 + w] = l[w] * rsc;
  }

  // coalesced store: this t's 625 floats are contiguous in out
  {
    const int t = t0 + wid;
    float* ob = out + ((size_t)n * TTT + t) * 625;
    for (int idx = lane; idx < 625; idx += 64) {
      int v = idx / VV;
      int w = idx - v * VV;
      ob[idx] = SIMW[v * 28 + w];
    }
  }
}

extern "C" void kernel_launch(void* const* d_in, const int* in_sizes, int n_in,
                              void* d_out, int out_size, void* d_ws, size_t ws_size,
                              hipStream_t stream) {
  const float* x1 = (const float*)d_in[0];
  const float* w1 = (const float*)d_in[1];
  const float* w2 = (const float*)d_in[2];
  const float* wm = (const float*)d_in[3];
  float* out = (float*)d_out;
  u16* mb = (u16*)d_ws;  // M (73,728 B) + wm bf16 (384 B)

  hipLaunchKernelGGL(prep, dim3(CC + 1), dim3(CC), 0, stream, w1, w2, wm, mb);
  hipLaunchKernelGGL(fused, dim3(GRID), dim3(384), LDS_BYTES, stream, x1, mb, out);
}

// Round 7
// 297.838 us; speedup vs baseline: 1.0418x; 1.0418x over previous
//
#include <hip/hip_runtime.h>
#include <cstdint>
#include <cstddef>

#define NN 64
#define CC 192
#define VV 25
#define TTT 300

// ---- workspace layout (u16 element indices unless noted) ----
#define WMEXT_OFF 36864      // 16x192 wmext (fallback mask-MFMA A operand)
#define MFRAG_OFF 40960      // M fragment-major: 72 frags x 64 lanes x 8 bf16
#define WML_OFF 77824        // wm linear bf16[192]
#define XB_BYTE_OFF 163840   // byte offset of Xb in ws
#define SLABB 9600           // per-t slab: 25 v-rows x 384B (bf16 [v][c])
#define XB_BYTES (19200LL*SLABB)  // 184,320,000

// k2
#define SWB 12672            // per-wave LDS: 9600 slab + 3072 Y/SIM scratch
#define K2_LDS (4*SWB)       // 50,688 -> 3 blocks/CU
// k0
#define K0_LDS 28800         // 400 cols x 72B

// fallback (round-3 fused_direct)
#define ROWB 384
#define D_XT_OFF 0
#define D_YT_OFF 31488
#define D_SIM_OFF 68352
#define D_MSK_OFF 76752
#define D_RS_OFF 77088
#define D_CS_OFF 77424
#define D_LDS_BYTES 77760
#define D_TB 3
#define D_NTB 100
#define D_GRID (NN*D_NTB)

typedef unsigned short u16;
typedef unsigned long long u64;
typedef short bf16x8 __attribute__((ext_vector_type(8)));
typedef float f32x4 __attribute__((ext_vector_type(4)));
typedef float f4 __attribute__((ext_vector_type(4)));
typedef int i32x4 __attribute__((ext_vector_type(4)));

__device__ __forceinline__ u16 f2bf(float x) {
  union { float f; uint32_t u; } v; v.f = x;
  uint32_t r = v.u + 0x7fffu + ((v.u >> 16) & 1u);
  return (u16)(r >> 16);
}
__device__ __forceinline__ float bf2f(u16 b) {
  union { uint32_t u; float f; } v; v.u = ((uint32_t)b) << 16; return v.f;
}
__device__ __forceinline__ u64 pack4(f32x4 a) {
  return (u64)f2bf(a[0]) | ((u64)f2bf(a[1]) << 16) |
         ((u64)f2bf(a[2]) << 32) | ((u64)f2bf(a[3]) << 48);
}
// XOR swizzle for 384B rows (row start bank-aligned without it)
__device__ __forceinline__ int swz(int row, int colb) {
  return row * ROWB + (colb ^ ((row & 7) << 4));
}

// prep: blocks 0..191: M[c1][c2]=sum_d w1[d][c1]w2[d][c2] in row-major (fallback)
// AND fragment-major (fast path). block 192: wmext (fallback) + wm linear.
__global__ __launch_bounds__(192) void prep(const float* __restrict__ w1,
                                            const float* __restrict__ w2,
                                            const float* __restrict__ wm,
                                            u16* __restrict__ mb) {
  int c2 = threadIdx.x, b = blockIdx.x;
  if (b < CC) {
    float s = 0.f;
    for (int d = 0; d < CC; ++d) s += w1[d * CC + b] * w2[d * CC + c2];
    u16 h = f2bf(s);
    mb[b * CC + c2] = h;  // row-major
    int cc = b >> 5, half = (b >> 4) & 1, lr = b & 15;
    int ks = c2 >> 5, l8 = (c2 & 31) >> 3, e = c2 & 7;
    int lane = l8 * 16 + lr;
    mb[MFRAG_OFF + (((cc * 2 + half) * 6 + ks) * 64 + lane) * 8 + e] = h;
  } else {
    u16 h = f2bf(wm[c2]);
    mb[WMEXT_OFF + c2] = h;
    #pragma unroll
    for (int r = 1; r < 16; ++r) mb[WMEXT_OFF + r * CC + c2] = 0;
    mb[WML_OFF + c2] = h;
  }
}

// k0: transpose/convert x1 [n][c][v][t] f32 -> Xb [n][t][v][c] bf16 (384B rows).
// Block = (n, c-tile 32, t-chunk 16). Reads: full 64B lines, each touched once.
// Writes: full 64B chunks. LDS tile [col=(tt*25+v)][72B] bounces the transpose.
__global__ __launch_bounds__(512) void k0(const float* __restrict__ x1,
                                          char* __restrict__ xb) {
  __shared__ char lt[K0_LDS];
  int bx = blockIdx.x;
  int n = bx / 114;
  int r = bx - n * 114;
  int ct = r / 19, tc = r - (r / 19) * 19;
  const float* base = x1 + (size_t)n * (CC * VV * TTT) + (size_t)(ct * 32) * (VV * TTT);
  int t0 = tc * 16;
  int tcw = (tc == 18) ? 12 : 16;
  int nq = tcw >> 2;
  int tid = threadIdx.x;
  u16* l16 = (u16*)lt;

  int jobs = 800 * nq;  // (32c x 25v rows) x t-quads
  for (int j = tid; j < jobs; j += 512) {
    int row = j / nq, q = j - row * nq;
    int cl = row / 25, v = row - cl * 25;
    f4 a = *(const f4*)(base + (size_t)cl * (VV * TTT) + v * TTT + t0 + q * 4);
    int colbase = (q * 4) * 25 + v;
    #pragma unroll
    for (int dt = 0; dt < 4; ++dt)
      l16[(colbase + dt * 25) * 36 + cl] = f2bf(a[dt]);
  }
  __syncthreads();

  int ojobs = tcw * 25 * 8;  // cols x 8B-subchunks
  for (int j = tid; j < ojobs; j += 512) {
    int col = j >> 3, s = j & 7;
    u64 d = *(const u64*)(lt + col * 72 + s * 8);
    int tt = col / 25, v = col - tt * 25;
    *(u64*)(xb + (size_t)((n * TTT + t0 + tt) * VV + v) * 384 + ct * 64 + s * 8) = d;
  }
}

// k2: 1 wave = 1 t, 4 waves/block, NO barriers. Wave stages its slab linearly
// (swizzled LDS writes), then c1-chunk loop {pass1 Y=M@X -> private Y-slice;
// pass2 sim += X^T Y; mask MFMA}; wave-private epilogue.
__global__ __launch_bounds__(256, 3) void k2(const char* __restrict__ xb,
                                             const u16* __restrict__ mb,
                                             float* __restrict__ out) {
  extern __shared__ char lds[];
  const int tid = threadIdx.x;
  const int wid = tid >> 6, lane = tid & 63, lr = lane & 15, lq = lane >> 4;
  char* WS = lds + wid * SWB;   // slab [25v(+garbage)][384B] swizzled
  char* YS = WS + 9600;         // Y-slice [32 w][80B] / epilogue SIM [27][28] f32

  // XCD-chunked bijective swizzle (4800 % 8 == 0)
  int b = blockIdx.x;
  int logical = (b & 7) * 600 + (b >> 3);
  int n = logical / 75, tq = logical - (logical / 75) * 75;
  int t = tq * 4 + wid;

  // ---- stage own slab: dense 16B global loads, swizzled LDS writes ----
  const char* sg = xb + (size_t)(n * TTT + t) * SLABB;
  for (int i = lane; i < 600; i += 64) {
    i32x4 d = *(const i32x4*)(sg + i * 16);
    int row = i / 24;
    int colb = (i - row * 24) * 16;
    *(i32x4*)(WS + row * 384 + (colb ^ ((row & 7) << 4))) = d;
  }
  // no barrier: same-wave program order + lgkmcnt

  f32x4 pacc[2][2], macc[2];
  #pragma unroll
  for (int i = 0; i < 2; ++i) {
    macc[i] = (f32x4){0.f, 0.f, 0.f, 0.f};
    #pragma unroll
    for (int jx = 0; jx < 2; ++jx) pacc[i][jx] = (f32x4){0.f, 0.f, 0.f, 0.f};
  }

  const u16* mf = mb + MFRAG_OFF;
  for (int cc = 0; cc < 6; ++cc) {
    // A-fragments: dense frag-major loads (same addresses for every wave)
    bf16x8 af0[6], af1[6];
    #pragma unroll
    for (int ks = 0; ks < 6; ++ks) {
      af0[ks] = *(const bf16x8*)(mf + ((cc * 12 + ks) * 64 + lane) * 8);
      af1[ks] = *(const bf16x8*)(mf + ((cc * 12 + 6 + ks) * 64 + lane) * 8);
    }
    bf16x8 wmf = *(const bf16x8*)(mb + WML_OFF + cc * 32 + lq * 8);

    // pass1: Y[c1-chunk 32][cols 32] -> private Y-slice
    #pragma unroll
    for (int j = 0; j < 2; ++j) {
      f32x4 y0 = (f32x4){0.f, 0.f, 0.f, 0.f};
      f32x4 y1 = (f32x4){0.f, 0.f, 0.f, 0.f};
      #pragma unroll
      for (int ks = 0; ks < 6; ++ks) {
        bf16x8 bb = *(const bf16x8*)(WS + swz(j * 16 + lr, ks * 64 + lq * 16));
        y0 = __builtin_amdgcn_mfma_f32_16x16x32_bf16(af0[ks], bb, y0, 0, 0, 0);
        y1 = __builtin_amdgcn_mfma_f32_16x16x32_bf16(af1[ks], bb, y1, 0, 0, 0);
      }
      *(u64*)(YS + (j * 16 + lr) * 80 + lq * 8) = pack4(y0);
      *(u64*)(YS + (j * 16 + lr) * 80 + 32 + lq * 8) = pack4(y1);
    }
    // pass2 + mask (K-accumulate over cc)
    #pragma unroll
    for (int vt = 0; vt < 2; ++vt) {
      bf16x8 A = *(const bf16x8*)(WS + swz(vt * 16 + lr, cc * 64 + lq * 16));
      macc[vt] = __builtin_amdgcn_mfma_f32_16x16x32_bf16(A, wmf, macc[vt], 0, 0, 0);
      #pragma unroll
      for (int wt = 0; wt < 2; ++wt) {
        bf16x8 B = *(const bf16x8*)(YS + (wt * 16 + lr) * 80 + lq * 16);
        pacc[vt][wt] = __builtin_amdgcn_mfma_f32_16x16x32_bf16(A, B, pacc[vt][wt], 0, 0, 0);
      }
    }
  }

  // ---- wave-private epilogue (Y-slice dead; reuse as SIM [27][28] f32) ----
  float* SIMW = (float*)YS;
  #pragma unroll
  for (int vt = 0; vt < 2; ++vt)
    #pragma unroll
    for (int wt = 0; wt < 2; ++wt) {
      int w = wt * 16 + lr;
      if (w < VV) {
        #pragma unroll
        for (int i = 0; i < 4; ++i) {
          int v = vt * 16 + lq * 4 + i;
          if (v < VV) SIMW[v * 28 + w] = pacc[vt][wt][i];
        }
      }
    }
  if (lr == 0) {  // mask row 26 (macc identical across lr)
    #pragma unroll
    for (int j = 0; j < 2; ++j)
      #pragma unroll
      for (int i = 0; i < 4; ++i) {
        int v = j * 16 + lq * 4 + i;
        if (v < VV) SIMW[26 * 28 + v] = macc[j][i];
      }
  }

  float rs = 0.f, cs = 0.f;
  if (lane < VV) {
    #pragma unroll
    for (int w = 0; w < VV; ++w) rs += SIMW[lane * 28 + w];
    #pragma unroll
    for (int v = 0; v < VV; ++v) cs += SIMW[v * 28 + lane];
    SIMW[25 * 28 + lane] = cs;
  }
  float x = (lane < VV) ? cs : 0.f;
  #pragma unroll
  for (int s = 1; s < 64; s <<= 1) x += __shfl_xor(x, s);
  const float tot = x;

  if (lane < VV) {
    const int v = lane;
    const float base = -rs * 0.04f + tot * 0.0016f;
    const float isc = 0.07216878364870323f;  // 1/sqrt(192)
    float l[VV];
    float mx = -1e30f;
    #pragma unroll
    for (int w = 0; w < VV; ++w) {
      float val = (SIMW[v * 28 + w] - SIMW[25 * 28 + w] * 0.04f + base) * isc +
                  SIMW[26 * 28 + w];
      l[w] = val;
      mx = fmaxf(mx, val);
    }
    float sum = 0.f;
    #pragma unroll
    for (int w = 0; w < VV; ++w) { float e = __expf(l[w] - mx); l[w] = e; sum += e; }
    float rsc = 1.0f / sum;
    #pragma unroll
    for (int w = 0; w < VV; ++w) SIMW[v * 28 + w] = l[w] * rsc;
  }

  float* ob = out + (size_t)(n * TTT + t) * 625;
  for (int idx = lane; idx < 625; idx += 64) {
    int v = idx / VV, w = idx - v * VV;
    ob[idx] = SIMW[v * 28 + w];
  }
}

// ---- fallback: round-3 fused (direct x1 staging) verbatim ----
__global__ __launch_bounds__(512, 4) void fused_direct(const float* __restrict__ x1,
                                                       const u16* __restrict__ mb,
                                                       float* __restrict__ out) {
  extern __shared__ char lds[];
  char* XT = lds + D_XT_OFF;
  char* YT = lds + D_YT_OFF;
  float* SIM = (float*)(lds + D_SIM_OFF);
  float* MSK = (float*)(lds + D_MSK_OFF);
  float* RS = (float*)(lds + D_RS_OFF);
  float* CS = (float*)(lds + D_CS_OFF);

  const int tid = threadIdx.x;
  const int wid = tid >> 6;
  const int lane = tid & 63;
  const int lr = lane & 15;
  const int lq = lane >> 4;

  int b = blockIdx.x;
  int logical = (b & 7) * (D_GRID / 8) + (b >> 3);
  int n = logical / D_NTB;
  int tb = logical - n * D_NTB;
  int t0 = tb * D_TB;

  const float* xb = x1 + (size_t)n * (CC * VV * TTT) + t0;
  for (int job = tid; job < 1200; job += 512) {
    int cq = job / 25, v = job - cq * 25;
    const float* p = xb + (cq * 4 * VV + v) * TTT;
    float a[4][D_TB];
    #pragma unroll
    for (int i = 0; i < 4; ++i) {
      const float* q = p + i * VV * TTT;
      a[i][0] = q[0]; a[i][1] = q[1]; a[i][2] = q[2];
    }
    #pragma unroll
    for (int tt = 0; tt < D_TB; ++tt) {
      u64 pk = (u64)f2bf(a[0][tt]) | ((u64)f2bf(a[1][tt]) << 16) |
               ((u64)f2bf(a[2][tt]) << 32) | ((u64)f2bf(a[3][tt]) << 48);
      *(u64*)(XT + swz(tt * 25 + v, cq * 8)) = pk;
    }
  }
  __syncthreads();

  const int mg = wid >> 1;
  const int ng = wid & 1;
  f32x4 acc[3][3];
  #pragma unroll
  for (int mt = 0; mt < 3; ++mt)
    #pragma unroll
    for (int nt = 0; nt < 3; ++nt) acc[mt][nt] = (f32x4){0.f, 0.f, 0.f, 0.f};

  #pragma unroll
  for (int ks = 0; ks < 6; ++ks) {
    bf16x8 bfr[3];
    #pragma unroll
    for (int nt = 0; nt < 3; ++nt) {
      int j = ng * 48 + nt * 16 + lr;
      bfr[nt] = *(const bf16x8*)(XT + swz(j, ks * 64 + lq * 16));
    }
    #pragma unroll
    for (int mt = 0; mt < 3; ++mt) {
      int c1 = mg * 48 + mt * 16 + lr;
      bf16x8 a = *(const bf16x8*)(mb + c1 * CC + ks * 32 + lq * 8);
      #pragma unroll
      for (int nt = 0; nt < 3; ++nt)
        acc[mt][nt] = __builtin_amdgcn_mfma_f32_16x16x32_bf16(a, bfr[nt], acc[mt][nt], 0, 0, 0);
    }
  }
  #pragma unroll
  for (int mt = 0; mt < 3; ++mt) {
    #pragma unroll
    for (int nt = 0; nt < 3; ++nt) {
      int j = ng * 48 + nt * 16 + lr;
      int c1b = (mg * 48 + mt * 16 + lq * 4) * 2;
      f32x4 a = acc[mt][nt];
      u64 pk = (u64)f2bf(a[0]) | ((u64)f2bf(a[1]) << 16) |
               ((u64)f2bf(a[2]) << 32) | ((u64)f2bf(a[3]) << 48);
      *(u64*)(YT + swz(j, c1b)) = pk;
    }
  }
  __syncthreads();

  for (int job = wid; job < 18; job += 8) {
    if (job < 12) {
      int tt = job >> 2, vt = (job >> 1) & 1, wt = job & 1;
      int ar = tt * 25 + vt * 16 + lr;
      int br = tt * 25 + wt * 16 + lr;
      f32x4 s = (f32x4){0.f, 0.f, 0.f, 0.f};
      #pragma unroll
      for (int ks = 0; ks < 6; ++ks) {
        bf16x8 a = *(const bf16x8*)(XT + swz(ar, ks * 64 + lq * 16));
        bf16x8 bb = *(const bf16x8*)(YT + swz(br, ks * 64 + lq * 16));
        s = __builtin_amdgcn_mfma_f32_16x16x32_bf16(a, bb, s, 0, 0, 0);
      }
      int w = wt * 16 + lr;
      if (w < VV) {
        #pragma unroll
        for (int i = 0; i < 4; ++i) {
          int v = vt * 16 + lq * 4 + i;
          if (v < VV) SIM[(tt * VV + v) * 28 + w] = s[i];
        }
      }
    } else {
      int m = job - 12;
      int tt = m >> 1, wt = m & 1;
      int br = tt * 25 + wt * 16 + lr;
      f32x4 s = (f32x4){0.f, 0.f, 0.f, 0.f};
      #pragma unroll
      for (int ks = 0; ks < 6; ++ks) {
        bf16x8 a = *(const bf16x8*)(mb + WMEXT_OFF + lr * CC + ks * 32 + lq * 8);
        bf16x8 bb = *(const bf16x8*)(XT + swz(br, ks * 64 + lq * 16));
        s = __builtin_amdgcn_mfma_f32_16x16x32_bf16(a, bb, s, 0, 0, 0);
      }
      int w = wt * 16 + lr;
      if (lq == 0 && w < VV) MSK[tt * 28 + w] = s[0];
    }
  }
  __syncthreads();

  if (tid < 150) {
    int q = tid / 25, idx = tid - q * 25;
    int tt = q >> 1;
    const float* sb = SIM + tt * VV * 28;
    float s = 0.f;
    if (q & 1) {
      #pragma unroll
      for (int w = 0; w < VV; ++w) s += sb[idx * 28 + w];
      RS[tt * 28 + idx] = s;
    } else {
      #pragma unroll
      for (int v = 0; v < VV; ++v) s += sb[v * 28 + idx];
      CS[tt * 28 + idx] = s;
    }
  }
  __syncthreads();

  if (tid < D_TB * VV) {
    int tt = tid / VV, v = tid - tt * VV;
    const float* sb = SIM + (tt * VV + v) * 28;
    const float* cs = CS + tt * 28;
    float tot = 0.f;
    #pragma unroll
    for (int w = 0; w < VV; ++w) tot += cs[w];
    const float base = -RS[tt * 28 + v] * 0.04f + tot * 0.0016f;
    const float isc = 0.07216878364870323f;
    float l[VV];
    float mx = -1e30f;
    #pragma unroll
    for (int w = 0; w < VV; ++w) {
      float val = (sb[w] - cs[w] * 0.04f + base) * isc + MSK[tt * 28 + w];
      l[w] = val;
      mx = fmaxf(mx, val);
    }
    float sum = 0.f;
    #pragma unroll
    for (int w = 0; w < VV; ++w) { float e = __expf(l[w] - mx); l[w] = e; sum += e; }
    float rsf = 1.0f / sum;
    float* o = out + (((size_t)n * TTT + t0 + tt) * VV + v) * VV;
    #pragma unroll
    for (int w = 0; w < VV; ++w) o[w] = l[w] * rsf;
  }
}

extern "C" void kernel_launch(void* const* d_in, const int* in_sizes, int n_in,
                              void* d_out, int out_size, void* d_ws, size_t ws_size,
                              hipStream_t stream) {
  const float* x1 = (const float*)d_in[0];
  const float* w1 = (const float*)d_in[1];
  const float* w2 = (const float*)d_in[2];
  const float* wm = (const float*)d_in[3];
  float* out = (float*)d_out;
  u16* mb = (u16*)d_ws;

  hipLaunchKernelGGL(prep, dim3(CC + 1), dim3(CC), 0, stream, w1, w2, wm, mb);
  if (ws_size >= (size_t)XB_BYTE_OFF + (size_t)XB_BYTES) {
    char* xb = (char*)d_ws + XB_BYTE_OFF;
    hipLaunchKernelGGL(k0, dim3(NN * 114), dim3(512), 0, stream, x1, xb);
    hipLaunchKernelGGL(k2, dim3(4800), dim3(256), K2_LDS, stream, xb, mb, out);
  } else {
    hipLaunchKernelGGL(fused_direct, dim3(D_GRID), dim3(512), D_LDS_BYTES, stream, x1, mb, out);
  }
}

// Round 8
// 294.794 us; speedup vs baseline: 1.0525x; 1.0103x over previous
//
#include <hip/hip_runtime.h>
#include <cstdint>
#include <cstddef>

#define NN 64
#define CC 192
#define VV 25
#define TTT 300

// ---- workspace layout (u16 element indices unless noted) ----
#define WMEXT_OFF 36864      // 16x192 wmext (fallback mask-MFMA A operand)
#define MFRAG_OFF 40960      // M fragment-major: 72 frags x 64 lanes x 8 bf16
#define WML_OFF 77824        // wm linear bf16[192]
#define XB_BYTE_OFF 163840   // byte offset of Xb in ws
#define SLABB 9600           // per-t slab: 25 v-rows x 384B (bf16 [v][c])
#define XB_BYTES (19200LL*SLABB)  // 184,320,000

// k0
#define K0_LDS 28800         // 400 cols x 72B

// fallback (round-3 fused_direct)
#define ROWB 384
#define D_XT_OFF 0
#define D_YT_OFF 31488
#define D_SIM_OFF 68352
#define D_MSK_OFF 76752
#define D_RS_OFF 77088
#define D_CS_OFF 77424
#define D_LDS_BYTES 77760
#define D_TB 3
#define D_NTB 100
#define D_GRID (NN*D_NTB)

typedef unsigned short u16;
typedef unsigned long long u64;
typedef short bf16x8 __attribute__((ext_vector_type(8)));
typedef float f32x4 __attribute__((ext_vector_type(4)));
typedef float f4 __attribute__((ext_vector_type(4)));

__device__ __forceinline__ u16 f2bf(float x) {
  union { float f; uint32_t u; } v; v.f = x;
  uint32_t r = v.u + 0x7fffu + ((v.u >> 16) & 1u);
  return (u16)(r >> 16);
}
__device__ __forceinline__ u64 pack4(f32x4 a) {
  return (u64)f2bf(a[0]) | ((u64)f2bf(a[1]) << 16) |
         ((u64)f2bf(a[2]) << 32) | ((u64)f2bf(a[3]) << 48);
}
// XOR swizzle for 384B rows (fallback path only)
__device__ __forceinline__ int swz(int row, int colb) {
  return row * ROWB + (colb ^ ((row & 7) << 4));
}

// prep: blocks 0..191: M[c1][c2]=sum_d w1[d][c1]w2[d][c2] row-major (fallback)
// AND fragment-major (fast path). block 192: wmext (fallback) + wm linear.
__global__ __launch_bounds__(192) void prep(const float* __restrict__ w1,
                                            const float* __restrict__ w2,
                                            const float* __restrict__ wm,
                                            u16* __restrict__ mb) {
  int c2 = threadIdx.x, b = blockIdx.x;
  if (b < CC) {
    float s = 0.f;
    for (int d = 0; d < CC; ++d) s += w1[d * CC + b] * w2[d * CC + c2];
    u16 h = f2bf(s);
    mb[b * CC + c2] = h;  // row-major
    int cc = b >> 5, half = (b >> 4) & 1, lr = b & 15;
    int ks = c2 >> 5, l8 = (c2 & 31) >> 3, e = c2 & 7;
    int lane = l8 * 16 + lr;
    mb[MFRAG_OFF + (((cc * 2 + half) * 6 + ks) * 64 + lane) * 8 + e] = h;
  } else {
    u16 h = f2bf(wm[c2]);
    mb[WMEXT_OFF + c2] = h;
    #pragma unroll
    for (int r = 1; r < 16; ++r) mb[WMEXT_OFF + r * CC + c2] = 0;
    mb[WML_OFF + c2] = h;
  }
}

// k0: transpose/convert x1 [n][c][v][t] f32 -> Xb [n][t][v][c] bf16 (384B rows).
// Block = (n, c-tile 32, t-chunk 16). Reads: full 64B lines, each touched once.
// Writes: full 64B chunks. LDS tile [col=(tt*25+v)][72B] bounces the transpose.
__global__ __launch_bounds__(512) void k0(const float* __restrict__ x1,
                                          char* __restrict__ xb) {
  __shared__ char lt[K0_LDS];
  int bx = blockIdx.x;
  int n = bx / 114;
  int r = bx - n * 114;
  int ct = r / 19, tc = r - (r / 19) * 19;
  const float* base = x1 + (size_t)n * (CC * VV * TTT) + (size_t)(ct * 32) * (VV * TTT);
  int t0 = tc * 16;
  int tcw = (tc == 18) ? 12 : 16;
  int nq = tcw >> 2;
  int tid = threadIdx.x;
  u16* l16 = (u16*)lt;

  int jobs = 800 * nq;  // (32c x 25v rows) x t-quads
  for (int j = tid; j < jobs; j += 512) {
    int row = j / nq, q = j - row * nq;
    int cl = row / 25, v = row - cl * 25;
    f4 a = *(const f4*)(base + (size_t)cl * (VV * TTT) + v * TTT + t0 + q * 4);
    int colbase = (q * 4) * 25 + v;
    #pragma unroll
    for (int dt = 0; dt < 4; ++dt)
      l16[(colbase + dt * 25) * 36 + cl] = f2bf(a[dt]);
  }
  __syncthreads();

  int ojobs = tcw * 25 * 8;  // cols x 8B-subchunks
  for (int j = tid; j < ojobs; j += 512) {
    int col = j >> 3, s = j & 7;
    u64 d = *(const u64*)(lt + col * 72 + s * 8);
    int tt = col / 25, v = col - tt * 25;
    *(u64*)(xb + (size_t)((n * TTT + t0 + tt) * VV + v) * 384 + ct * 64 + s * 8) = d;
  }
}

// k2: 1 wave = 1 t, 4 waves/block, NO barriers, NO X-LDS.
// The whole 25x192 slab lives in 12 register fragments loaded straight from
// global (fragment == dense 16 rows x 64B read). Same regs serve as pass1 B
// (Y = M @ X, all 6 c1-chunks) and pass2 A (sim += X^T Y). Only LDS: 3KB/wave
// Y-bounce (C-layout -> B-layout) reused as SIM for the epilogue.
__global__ __launch_bounds__(256, 3) void k2(const char* __restrict__ xb,
                                             const u16* __restrict__ mb,
                                             float* __restrict__ out) {
  __shared__ char lds[4 * 3072];
  const int tid = threadIdx.x;
  const int wid = tid >> 6, lane = tid & 63, lr = lane & 15, lq = lane >> 4;
  char* YS = lds + wid * 3072;   // Y-slice [32 w][80B] / epilogue SIM [27][28] f32

  // XCD-chunked bijective swizzle (4800 % 8 == 0)
  int b = blockIdx.x;
  int logical = (b & 7) * 600 + (b >> 3);
  int n = logical / 75, tq = logical - (logical / 75) * 75;
  int t = tq * 4 + wid;

  // ---- load slab into 12 register fragments (rows 25..31 = garbage, masked) ----
  const char* sg = xb + (size_t)(n * TTT + t) * SLABB;
  bf16x8 sf[2][6];
  #pragma unroll
  for (int j = 0; j < 2; ++j)
    #pragma unroll
    for (int ks = 0; ks < 6; ++ks)
      sf[j][ks] = *(const bf16x8*)(sg + (j * 16 + lr) * 384 + ks * 64 + lq * 16);

  f32x4 pacc[2][2], macc[2];
  #pragma unroll
  for (int i = 0; i < 2; ++i) {
    macc[i] = (f32x4){0.f, 0.f, 0.f, 0.f};
    #pragma unroll
    for (int jx = 0; jx < 2; ++jx) pacc[i][jx] = (f32x4){0.f, 0.f, 0.f, 0.f};
  }

  const u16* mf = mb + MFRAG_OFF;
  for (int cc = 0; cc < 6; ++cc) {
    // A-fragments of M (identical addresses for all waves -> L1 broadcast)
    bf16x8 af0[6], af1[6];
    #pragma unroll
    for (int ks = 0; ks < 6; ++ks) {
      af0[ks] = *(const bf16x8*)(mf + ((cc * 12 + ks) * 64 + lane) * 8);
      af1[ks] = *(const bf16x8*)(mf + ((cc * 12 + 6 + ks) * 64 + lane) * 8);
    }
    bf16x8 wmf = *(const bf16x8*)(mb + WML_OFF + cc * 32 + lq * 8);

    // pass1: Y[c1-chunk 32][cols 32] -> Y-bounce (B comes from registers)
    #pragma unroll
    for (int j = 0; j < 2; ++j) {
      f32x4 y0 = (f32x4){0.f, 0.f, 0.f, 0.f};
      f32x4 y1 = (f32x4){0.f, 0.f, 0.f, 0.f};
      #pragma unroll
      for (int ks = 0; ks < 6; ++ks) {
        y0 = __builtin_amdgcn_mfma_f32_16x16x32_bf16(af0[ks], sf[j][ks], y0, 0, 0, 0);
        y1 = __builtin_amdgcn_mfma_f32_16x16x32_bf16(af1[ks], sf[j][ks], y1, 0, 0, 0);
      }
      *(u64*)(YS + (j * 16 + lr) * 80 + lq * 8) = pack4(y0);
      *(u64*)(YS + (j * 16 + lr) * 80 + 32 + lq * 8) = pack4(y1);
    }
    // pass2 + mask (A from registers; K-accumulate over cc)
    #pragma unroll
    for (int vt = 0; vt < 2; ++vt) {
      bf16x8 A = sf[vt][cc];
      macc[vt] = __builtin_amdgcn_mfma_f32_16x16x32_bf16(A, wmf, macc[vt], 0, 0, 0);
      #pragma unroll
      for (int wt = 0; wt < 2; ++wt) {
        bf16x8 B = *(const bf16x8*)(YS + (wt * 16 + lr) * 80 + lq * 16);
        pacc[vt][wt] = __builtin_amdgcn_mfma_f32_16x16x32_bf16(A, B, pacc[vt][wt], 0, 0, 0);
      }
    }
  }

  // ---- wave-private epilogue (Y-bounce dead; reuse as SIM [27][28] f32) ----
  float* SIMW = (float*)YS;
  #pragma unroll
  for (int vt = 0; vt < 2; ++vt)
    #pragma unroll
    for (int wt = 0; wt < 2; ++wt) {
      int w = wt * 16 + lr;
      if (w < VV) {
        #pragma unroll
        for (int i = 0; i < 4; ++i) {
          int v = vt * 16 + lq * 4 + i;
          if (v < VV) SIMW[v * 28 + w] = pacc[vt][wt][i];
        }
      }
    }
  if (lr == 0) {  // mask row 26 (macc identical across lr)
    #pragma unroll
    for (int j = 0; j < 2; ++j)
      #pragma unroll
      for (int i = 0; i < 4; ++i) {
        int v = j * 16 + lq * 4 + i;
        if (v < VV) SIMW[26 * 28 + v] = macc[j][i];
      }
  }

  float rs = 0.f, cs = 0.f;
  if (lane < VV) {
    #pragma unroll
    for (int w = 0; w < VV; ++w) rs += SIMW[lane * 28 + w];
    #pragma unroll
    for (int v = 0; v < VV; ++v) cs += SIMW[v * 28 + lane];
    SIMW[25 * 28 + lane] = cs;
  }
  float x = (lane < VV) ? cs : 0.f;
  #pragma unroll
  for (int s = 1; s < 64; s <<= 1) x += __shfl_xor(x, s);
  const float tot = x;

  if (lane < VV) {
    const int v = lane;
    const float base = -rs * 0.04f + tot * 0.0016f;
    const float isc = 0.07216878364870323f;  // 1/sqrt(192)
    float l[VV];
    float mx = -1e30f;
    #pragma unroll
    for (int w = 0; w < VV; ++w) {
      float val = (SIMW[v * 28 + w] - SIMW[25 * 28 + w] * 0.04f + base) * isc +
                  SIMW[26 * 28 + w];
      l[w] = val;
      mx = fmaxf(mx, val);
    }
    float sum = 0.f;
    #pragma unroll
    for (int w = 0; w < VV; ++w) { float e = __expf(l[w] - mx); l[w] = e; sum += e; }
    float rsc = 1.0f / sum;
    #pragma unroll
    for (int w = 0; w < VV; ++w) SIMW[v * 28 + w] = l[w] * rsc;
  }

  float* ob = out + (size_t)(n * TTT + t) * 625;
  for (int idx = lane; idx < 625; idx += 64) {
    int v = idx / VV, w = idx - v * VV;
    ob[idx] = SIMW[v * 28 + w];
  }
}

// ---- fallback: round-3 fused (direct x1 staging) verbatim ----
__global__ __launch_bounds__(512, 4) void fused_direct(const float* __restrict__ x1,
                                                       const u16* __restrict__ mb,
                                                       float* __restrict__ out) {
  extern __shared__ char lds[];
  char* XT = lds + D_XT_OFF;
  char* YT = lds + D_YT_OFF;
  float* SIM = (float*)(lds + D_SIM_OFF);
  float* MSK = (float*)(lds + D_MSK_OFF);
  float* RS = (float*)(lds + D_RS_OFF);
  float* CS = (float*)(lds + D_CS_OFF);

  const int tid = threadIdx.x;
  const int wid = tid >> 6;
  const int lane = tid & 63;
  const int lr = lane & 15;
  const int lq = lane >> 4;

  int b = blockIdx.x;
  int logical = (b & 7) * (D_GRID / 8) + (b >> 3);
  int n = logical / D_NTB;
  int tb = logical - n * D_NTB;
  int t0 = tb * D_TB;

  const float* xb = x1 + (size_t)n * (CC * VV * TTT) + t0;
  for (int job = tid; job < 1200; job += 512) {
    int cq = job / 25, v = job - cq * 25;
    const float* p = xb + (cq * 4 * VV + v) * TTT;
    float a[4][D_TB];
    #pragma unroll
    for (int i = 0; i < 4; ++i) {
      const float* q = p + i * VV * TTT;
      a[i][0] = q[0]; a[i][1] = q[1]; a[i][2] = q[2];
    }
    #pragma unroll
    for (int tt = 0; tt < D_TB; ++tt) {
      u64 pk = (u64)f2bf(a[0][tt]) | ((u64)f2bf(a[1][tt]) << 16) |
               ((u64)f2bf(a[2][tt]) << 32) | ((u64)f2bf(a[3][tt]) << 48);
      *(u64*)(XT + swz(tt * 25 + v, cq * 8)) = pk;
    }
  }
  __syncthreads();

  const int mg = wid >> 1;
  const int ng = wid & 1;
  f32x4 acc[3][3];
  #pragma unroll
  for (int mt = 0; mt < 3; ++mt)
    #pragma unroll
    for (int nt = 0; nt < 3; ++nt) acc[mt][nt] = (f32x4){0.f, 0.f, 0.f, 0.f};

  #pragma unroll
  for (int ks = 0; ks < 6; ++ks) {
    bf16x8 bfr[3];
    #pragma unroll
    for (int nt = 0; nt < 3; ++nt) {
      int j = ng * 48 + nt * 16 + lr;
      bfr[nt] = *(const bf16x8*)(XT + swz(j, ks * 64 + lq * 16));
    }
    #pragma unroll
    for (int mt = 0; mt < 3; ++mt) {
      int c1 = mg * 48 + mt * 16 + lr;
      bf16x8 a = *(const bf16x8*)(mb + c1 * CC + ks * 32 + lq * 8);
      #pragma unroll
      for (int nt = 0; nt < 3; ++nt)
        acc[mt][nt] = __builtin_amdgcn_mfma_f32_16x16x32_bf16(a, bfr[nt], acc[mt][nt], 0, 0, 0);
    }
  }
  #pragma unroll
  for (int mt = 0; mt < 3; ++mt) {
    #pragma unroll
    for (int nt = 0; nt < 3; ++nt) {
      int j = ng * 48 + nt * 16 + lr;
      int c1b = (mg * 48 + mt * 16 + lq * 4) * 2;
      f32x4 a = acc[mt][nt];
      u64 pk = (u64)f2bf(a[0]) | ((u64)f2bf(a[1]) << 16) |
               ((u64)f2bf(a[2]) << 32) | ((u64)f2bf(a[3]) << 48);
      *(u64*)(YT + swz(j, c1b)) = pk;
    }
  }
  __syncthreads();

  for (int job = wid; job < 18; job += 8) {
    if (job < 12) {
      int tt = job >> 2, vt = (job >> 1) & 1, wt = job & 1;
      int ar = tt * 25 + vt * 16 + lr;
      int br = tt * 25 + wt * 16 + lr;
      f32x4 s = (f32x4){0.f, 0.f, 0.f, 0.f};
      #pragma unroll
      for (int ks = 0; ks < 6; ++ks) {
        bf16x8 a = *(const bf16x8*)(XT + swz(ar, ks * 64 + lq * 16));
        bf16x8 bb = *(const bf16x8*)(YT + swz(br, ks * 64 + lq * 16));
        s = __builtin_amdgcn_mfma_f32_16x16x32_bf16(a, bb, s, 0, 0, 0);
      }
      int w = wt * 16 + lr;
      if (w < VV) {
        #pragma unroll
        for (int i = 0; i < 4; ++i) {
          int v = vt * 16 + lq * 4 + i;
          if (v < VV) SIM[(tt * VV + v) * 28 + w] = s[i];
        }
      }
    } else {
      int m = job - 12;
      int tt = m >> 1, wt = m & 1;
      int br = tt * 25 + wt * 16 + lr;
      f32x4 s = (f32x4){0.f, 0.f, 0.f, 0.f};
      #pragma unroll
      for (int ks = 0; ks < 6; ++ks) {
        bf16x8 a = *(const bf16x8*)(mb + WMEXT_OFF + lr * CC + ks * 32 + lq * 8);
        bf16x8 bb = *(const bf16x8*)(XT + swz(br, ks * 64 + lq * 16));
        s = __builtin_amdgcn_mfma_f32_16x16x32_bf16(a, bb, s, 0, 0, 0);
      }
      int w = wt * 16 + lr;
      if (lq == 0 && w < VV) MSK[tt * 28 + w] = s[0];
    }
  }
  __syncthreads();

  if (tid < 150) {
    int q = tid / 25, idx = tid - q * 25;
    int tt = q >> 1;
    const float* sb = SIM + tt * VV * 28;
    float s = 0.f;
    if (q & 1) {
      #pragma unroll
      for (int w = 0; w < VV; ++w) s += sb[idx * 28 + w];
      RS[tt * 28 + idx] = s;
    } else {
      #pragma unroll
      for (int v = 0; v < VV; ++v) s += sb[v * 28 + idx];
      CS[tt * 28 + idx] = s;
    }
  }
  __syncthreads();

  if (tid < D_TB * VV) {
    int tt = tid / VV, v = tid - tt * VV;
    const float* sb = SIM + (tt * VV + v) * 28;
    const float* cs = CS + tt * 28;
    float tot = 0.f;
    #pragma unroll
    for (int w = 0; w < VV; ++w) tot += cs[w];
    const float base = -RS[tt * 28 + v] * 0.04f + tot * 0.0016f;
    const float isc = 0.07216878364870323f;
    float l[VV];
    float mx = -1e30f;
    #pragma unroll
    for (int w = 0; w < VV; ++w) {
      float val = (sb[w] - cs[w] * 0.04f + base) * isc + MSK[tt * 28 + w];
      l[w] = val;
      mx = fmaxf(mx, val);
    }
    float sum = 0.f;
    #pragma unroll
    for (int w = 0; w < VV; ++w) { float e = __expf(l[w] - mx); l[w] = e; sum += e; }
    float rsf = 1.0f / sum;
    float* o = out + (((size_t)n * TTT + t0 + tt) * VV + v) * VV;
    #pragma unroll
    for (int w = 0; w < VV; ++w) o[w] = l[w] * rsf;
  }
}

extern "C" void kernel_launch(void* const* d_in, const int* in_sizes, int n_in,
                              void* d_out, int out_size, void* d_ws, size_t ws_size,
                              hipStream_t stream) {
  const float* x1 = (const float*)d_in[0];
  const float* w1 = (const float*)d_in[1];
  const float* w2 = (const float*)d_in[2];
  const float* wm = (const float*)d_in[3];
  float* out = (float*)d_out;
  u16* mb = (u16*)d_ws;

  hipLaunchKernelGGL(prep, dim3(CC + 1), dim3(CC), 0, stream, w1, w2, wm, mb);
  // +32KB slack: k2's garbage rows 25..31 of the final slab read past XB end.
  if (ws_size >= (size_t)XB_BYTE_OFF + (size_t)XB_BYTES + 32768) {
    char* xb = (char*)d_ws + XB_BYTE_OFF;
    hipLaunchKernelGGL(k0, dim3(NN * 114), dim3(512), 0, stream, x1, xb);
    hipLaunchKernelGGL(k2, dim3(4800), dim3(256), 0, stream, xb, mb, out);
  } else {
    hipLaunchKernelGGL(fused_direct, dim3(D_GRID), dim3(512), D_LDS_BYTES, stream, x1, mb, out);
  }
}

// Round 9
// 211.064 us; speedup vs baseline: 1.4701x; 1.3967x over previous
//
#include <hip/hip_runtime.h>
#include <cstdint>
#include <cstddef>

#define NN 64
#define CC 192
#define VV 25
#define TTT 300
#define TC 8            // t per block, 1 per wave
#define NTC 38          // ceil(300/8); last chunk has 4 real t
#define GRID (NN*NTC)   // 2432 = 8*304

// workspace (u16 element offsets)
#define MFRAG_OFF 40960 // M fragment-major: 72 frags x 64 lanes x 8 bf16
#define WML_OFF 77824   // wm linear bf16[192]

// LDS: transpose tile [208 cols][80B] + 8 x 3KB wave scratch
#define TILE_BYTES 16640
#define LDS_BYTES (TILE_BYTES + 8*3072)   // 41,216 -> 2 blocks/CU (VGPR<=128)

typedef unsigned short u16;
typedef unsigned long long u64;
typedef short bf16x8 __attribute__((ext_vector_type(8)));
typedef float f32x4 __attribute__((ext_vector_type(4)));
typedef float f4 __attribute__((ext_vector_type(4)));

__device__ __forceinline__ u16 f2bf(float x) {
  union { float f; uint32_t u; } v; v.f = x;
  uint32_t r = v.u + 0x7fffu + ((v.u >> 16) & 1u);
  return (u16)(r >> 16);
}
__device__ __forceinline__ u64 pack4(f32x4 a) {
  return (u64)f2bf(a[0]) | ((u64)f2bf(a[1]) << 16) |
         ((u64)f2bf(a[2]) << 32) | ((u64)f2bf(a[3]) << 48);
}

// prep: blocks 0..191 -> M fragment-major; block 192 -> wm linear bf16.
__global__ __launch_bounds__(192) void prep(const float* __restrict__ w1,
                                            const float* __restrict__ w2,
                                            const float* __restrict__ wm,
                                            u16* __restrict__ mb) {
  int c2 = threadIdx.x, b = blockIdx.x;
  if (b < CC) {
    float s = 0.f;
    for (int d = 0; d < CC; ++d) s += w1[d * CC + b] * w2[d * CC + c2];
    u16 h = f2bf(s);
    int cc = b >> 5, half = (b >> 4) & 1, lr = b & 15;
    int ks = c2 >> 5, l8 = (c2 & 31) >> 3, e = c2 & 7;
    int lane = l8 * 16 + lr;
    mb[MFRAG_OFF + (((cc * 2 + half) * 6 + ks) * 64 + lane) * 8 + e] = h;
  } else {
    mb[WML_OFF + c2] = f2bf(wm[c2]);
  }
}

// fused: block = (n, 8 t). 6 c-tile rounds of {dense-read stage -> LDS transpose
// tile -> barrier -> fragment reads into sf regs -> barrier}, then barrier-free
// register compute per wave (pass1 Y=M@X via Y-bounce, pass2 sim += X^T Y,
// mask-MFMA, stats centering, softmax, coalesced store).
__global__ __launch_bounds__(512, 4) void fused(const float* __restrict__ x1,
                                                const u16* __restrict__ mb,
                                                float* __restrict__ out) {
  extern __shared__ char lds[];
  u16* tile16 = (u16*)lds;
  const int tid = threadIdx.x;
  const int wid = tid >> 6, lane = tid & 63, lr = lane & 15, lq = lane >> 4;
  char* YS = lds + TILE_BYTES + wid * 3072;  // Y-bounce / epilogue SIM [27][28] f32

  // XCD-chunked bijective swizzle (GRID = 8*304): adjacent t-chunks same XCD.
  int b = blockIdx.x;
  int logical = (b & 7) * (GRID / 8) + (b >> 3);
  int n = logical / NTC;
  int ch = logical - n * NTC;
  int t0 = ch * TC;
  int t = t0 + wid;

  const float* xb = x1 + (size_t)n * (CC * VV * TTT) + t0;

  // ---- 6 c-tile rounds: stage + fragment harvest ----
  bf16x8 sf[2][6];
  #pragma unroll
  for (int ct = 0; ct < 6; ++ct) {
    for (int job = tid; job < 1600; job += 512) {
      int row = job >> 1, q = job & 1;            // row=(cl,v), q = t-quad
      int cl = row / 25, v = row - cl * 25;
      int qq = (t0 + 4 * q + 4 <= TTT) ? q : 0;   // clamp last chunk (valid mem)
      f4 a = *(const f4*)(xb + (size_t)(ct * 32 + cl) * (VV * TTT) + v * TTT + qq * 4);
      #pragma unroll
      for (int dt = 0; dt < 4; ++dt)
        tile16[((q * 4 + dt) * 25 + v) * 40 + cl] = f2bf(a[dt]);
    }
    __syncthreads();
    #pragma unroll
    for (int j = 0; j < 2; ++j)
      sf[j][ct] = *(const bf16x8*)(lds + (wid * VV + j * 16 + lr) * 80 + lq * 16);
    __syncthreads();
  }

  // ---- register compute (no barriers) ----
  f32x4 pacc[2][2], macc[2];
  #pragma unroll
  for (int i = 0; i < 2; ++i) {
    macc[i] = (f32x4){0.f, 0.f, 0.f, 0.f};
    #pragma unroll
    for (int jx = 0; jx < 2; ++jx) pacc[i][jx] = (f32x4){0.f, 0.f, 0.f, 0.f};
  }

  const u16* mf = mb + MFRAG_OFF;
  #pragma unroll
  for (int cc = 0; cc < 6; ++cc) {
    // pass1: Y[c1-chunk 32][32 cols]; ks-outer so af loads once, 4 y-accs live
    f32x4 y00 = (f32x4){0.f,0.f,0.f,0.f}, y01 = y00, y10 = y00, y11 = y00;
    #pragma unroll
    for (int ks = 0; ks < 6; ++ks) {
      bf16x8 a0 = *(const bf16x8*)(mf + ((cc * 12 + ks) * 64 + lane) * 8);
      bf16x8 a1 = *(const bf16x8*)(mf + ((cc * 12 + 6 + ks) * 64 + lane) * 8);
      y00 = __builtin_amdgcn_mfma_f32_16x16x32_bf16(a0, sf[0][ks], y00, 0, 0, 0);
      y01 = __builtin_amdgcn_mfma_f32_16x16x32_bf16(a1, sf[0][ks], y01, 0, 0, 0);
      y10 = __builtin_amdgcn_mfma_f32_16x16x32_bf16(a0, sf[1][ks], y10, 0, 0, 0);
      y11 = __builtin_amdgcn_mfma_f32_16x16x32_bf16(a1, sf[1][ks], y11, 0, 0, 0);
    }
    *(u64*)(YS + (lr) * 80 + lq * 8) = pack4(y00);
    *(u64*)(YS + (lr) * 80 + 32 + lq * 8) = pack4(y01);
    *(u64*)(YS + (16 + lr) * 80 + lq * 8) = pack4(y10);
    *(u64*)(YS + (16 + lr) * 80 + 32 + lq * 8) = pack4(y11);

    // pass2 + mask (same-wave ordering)
    bf16x8 wmf = *(const bf16x8*)(mb + WML_OFF + cc * 32 + lq * 8);
    #pragma unroll
    for (int vt = 0; vt < 2; ++vt) {
      bf16x8 A = sf[vt][cc];
      macc[vt] = __builtin_amdgcn_mfma_f32_16x16x32_bf16(A, wmf, macc[vt], 0, 0, 0);
      #pragma unroll
      for (int wt = 0; wt < 2; ++wt) {
        bf16x8 B = *(const bf16x8*)(YS + (wt * 16 + lr) * 80 + lq * 16);
        pacc[vt][wt] = __builtin_amdgcn_mfma_f32_16x16x32_bf16(A, B, pacc[vt][wt], 0, 0, 0);
      }
    }
  }

  // ---- wave-private epilogue (Y-bounce dead; reuse as SIM [27][28] f32) ----
  float* SIMW = (float*)YS;
  #pragma unroll
  for (int vt = 0; vt < 2; ++vt)
    #pragma unroll
    for (int wt = 0; wt < 2; ++wt) {
      int w = wt * 16 + lr;
      if (w < VV) {
        #pragma unroll
        for (int i = 0; i < 4; ++i) {
          int v = vt * 16 + lq * 4 + i;
          if (v < VV) SIMW[v * 28 + w] = pacc[vt][wt][i];
        }
      }
    }
  if (lr == 0) {  // mask row 26 (macc identical across lr)
    #pragma unroll
    for (int j = 0; j < 2; ++j)
      #pragma unroll
      for (int i = 0; i < 4; ++i) {
        int v = j * 16 + lq * 4 + i;
        if (v < VV) SIMW[26 * 28 + v] = macc[j][i];
      }
  }

  float rs = 0.f, cs = 0.f;
  if (lane < VV) {
    #pragma unroll
    for (int w = 0; w < VV; ++w) rs += SIMW[lane * 28 + w];
    #pragma unroll
    for (int v = 0; v < VV; ++v) cs += SIMW[v * 28 + lane];
    SIMW[25 * 28 + lane] = cs;
  }
  float x = (lane < VV) ? cs : 0.f;
  #pragma unroll
  for (int s = 1; s < 64; s <<= 1) x += __shfl_xor(x, s);
  const float tot = x;

  if (lane < VV) {
    const int v = lane;
    const float base = -rs * 0.04f + tot * 0.0016f;
    const float isc = 0.07216878364870323f;  // 1/sqrt(192)
    float l[VV];
    float mx = -1e30f;
    #pragma unroll
    for (int w = 0; w < VV; ++w) {
      float val = (SIMW[v * 28 + w] - SIMW[25 * 28 + w] * 0.04f + base) * isc +
                  SIMW[26 * 28 + w];
      l[w] = val;
      mx = fmaxf(mx, val);
    }
    float sum = 0.f;
    #pragma unroll
    for (int w = 0; w < VV; ++w) { float e = __expf(l[w] - mx); l[w] = e; sum += e; }
    float rsc = 1.0f / sum;
    #pragma unroll
    for (int w = 0; w < VV; ++w) SIMW[v * 28 + w] = l[w] * rsc;
  }

  if (t < TTT) {
    float* ob = out + (size_t)(n * TTT + t) * 625;
    for (int idx = lane; idx < 625; idx += 64) {
      int v = idx / VV, w = idx - v * VV;
      ob[idx] = SIMW[v * 28 + w];
    }
  }
}

extern "C" void kernel_launch(void* const* d_in, const int* in_sizes, int n_in,
                              void* d_out, int out_size, void* d_ws, size_t ws_size,
                              hipStream_t stream) {
  const float* x1 = (const float*)d_in[0];
  const float* w1 = (const float*)d_in[1];
  const float* w2 = (const float*)d_in[2];
  const float* wm = (const float*)d_in[3];
  float* out = (float*)d_out;
  u16* mb = (u16*)d_ws;  // ~156 KB used

  hipLaunchKernelGGL(prep, dim3(CC + 1), dim3(CC), 0, stream, w1, w2, wm, mb);
  hipLaunchKernelGGL(fused, dim3(GRID), dim3(512), LDS_BYTES, stream, x1, mb, out);
}